// Round 9
// baseline (109.243 us; speedup 1.0000x reference)
//
#include <hip/hip_runtime.h>
#include <cstdint>

#define B_   32
#define CIN  256
#define COUT 256
#define H_   56
#define W_   56
#define HP   58          // padded spatial dim (pad=1 each side)
#define HW   (H_ * W_)   // 3136

typedef int v4i  __attribute__((ext_vector_type(4)));
typedef int v16i __attribute__((ext_vector_type(16)));

// ==================================================================
// XNOR conv via i8 MFMA: a,w in {+1,-1}; zero-pad = i8 0 (exact).
// ==================================================================

// ---- pack_a8: NCHW fp32 -> padded NHWC i8. A8[b][hh][ww][ci] ----
__global__ __launch_bounds__(256) void pack_a8_kernel(
    const float* __restrict__ x, const float* __restrict__ alpha,
    char* __restrict__ A8) {
  const int w = threadIdx.x & 63;
  const int q = threadIdx.x >> 6;
  const int hh = blockIdx.x * 4 + q;
  const int b = blockIdx.y;
  if (hh >= HP) return;
  char* rowbase = A8 + (size_t)(b * HP + hh) * (HP * 256);
  const uint4 z = make_uint4(0u, 0u, 0u, 0u);
  if (hh == 0 || hh == HP - 1) {           // border row: all zeros
    for (int i = w; i < HP * 16; i += 64) *(uint4*)(rowbase + i * 16) = z;
    return;
  }
  const int h = hh - 1;
  if (w < W_) {
    char* dst = rowbase + (w + 1) * 256;
    const float* xp = x + (size_t)b * CIN * HW + h * W_ + w;
    for (int cw = 0; cw < 16; ++cw) {      // 16B of channels per iter
      uint32_t wd[4];
      #pragma unroll
      for (int u = 0; u < 4; ++u) {
        uint32_t word = 0;
        #pragma unroll
        for (int bb = 0; bb < 4; ++bb) {
          int c = cw * 16 + u * 4 + bb;
          float v = xp[(size_t)c * HW];
          word |= ((v > alpha[c]) ? 0x01u : 0xFFu) << (bb * 8);
        }
        wd[u] = word;
      }
      *(uint4*)(dst + cw * 16) = *(uint4*)wd;
    }
  } else if (w == 56 || w == 57) {         // border pixels ww=0 / ww=57
    char* dst = rowbase + ((w == 56) ? 0 : (HP - 1)) * 256;
    #pragma unroll
    for (int i = 0; i < 16; ++i) *(uint4*)(dst + i * 16) = z;
  }
}

// ---- pack_w8: W in exact B-fragment form (HW-verified, absmax 0) ----
// Wf[((tap*8 + kc)*8 + ng)*64 + lane]: co = ng*32 + (lane&31),
// ci = kc*32 + (lane>>5)*16 + byte j
__global__ __launch_bounds__(256) void pack_w8_kernel(
    const float* __restrict__ wt, v4i* __restrict__ Wf) {
  int id = blockIdx.x * 256 + threadIdx.x;   // 36864 total
  int lane = id & 63;
  int ng = (id >> 6) & 7;
  int kc = (id >> 9) & 7;
  int tap = id >> 12;
  if (tap >= 9) return;
  int kh = tap / 3, kw = tap - kh * 3;
  int co = ng * 32 + (lane & 31);
  int cib = kc * 32 + (lane >> 5) * 16;
  uint32_t wd[4];
  #pragma unroll
  for (int u = 0; u < 4; ++u) {
    uint32_t word = 0;
    #pragma unroll
    for (int bb = 0; bb < 4; ++bb) {
      int ci = cib + u * 4 + bb;
      float v = wt[((size_t)(co * CIN + ci) * 3 + kh) * 3 + kw];
      word |= ((v > 0.0f) ? 0x01u : 0xFFu) << (bb * 8);
    }
    wd[u] = word;
  }
  Wf[id] = *(v4i*)wd;
}

// ---- conv_mfma v6: (kc,kw)-batched, minimal ds_reads, low VGPR ----
// Block: 256 thr / 4 waves. Tile M128 (2 oh x 64 ow full row) x N256.
// Wave: M128 x N64; acc[4 mg][2 ng] v16i = 128 AGPR.
// Batch t = kc*3+kw (24 total): 8 af ds_reads (4 rr x 2 owh, EACH READ
// EXACTLY ONCE over the kernel: 192/wave vs 288 before), 6 bf L2 loads
// (ping-pong prefetched one batch ahead), 24 MFMAs (3 kh x 4 mg x 2 ng).
// Live arch VGPR ~100 < 128 cap -> scheduler can hoist ds_reads above
// the MFMA cluster instead of sinking them to just-before-use (the
// r6-r8 35%-MfmaUtil stall: ~120cy LDS latency exposed per MFMA).
// s_setprio(1) around MFMA clusters (T5).
__global__ __launch_bounds__(256, 2) void conv_mfma_kernel(
    const char* __restrict__ A8, const v4i* __restrict__ Wf,
    float* __restrict__ out) {
  __shared__ alignas(16) char lds[67584];  // slab 59392 | scr 4 x 16896
  const int tid = threadIdx.x;
  const int lane = tid & 63;
  const int l31 = lane & 31;
  const int hi  = lane >> 5;
  const int wn  = tid >> 6;

  const int ohp = blockIdx.x % 28;
  const int b   = blockIdx.x / 28;
  const int oh0 = ohp * 2;

  // ---- fill transposed slab: phys = ((gr*4 + rr)*58 + ww)*16 ----
  {
    const char* src0 = A8 + (size_t)(b * HP + oh0) * (HP * 256);
    for (int i = tid; i < 4 * 58 * 16; i += 256) {
      int gr = i & 15;
      int pix = i >> 4;              // rr*58 + ww
      int rr = pix / 58;
      int ww = pix - rr * 58;
      uint4 v = *(const uint4*)(src0 + (size_t)(rr * HP + ww) * 256 + gr * 16);
      *(uint4*)(lds + ((gr * 4 + rr) * 58 + ww) * 16) = v;
    }
  }
  __syncthreads();

  v16i acc[4][2];
  #pragma unroll
  for (int m = 0; m < 4; ++m)
    #pragma unroll
    for (int n = 0; n < 2; ++n)
      #pragma unroll
      for (int e = 0; e < 16; ++e) acc[m][n][e] = 0;

  // thread-constant bases (compile-time offsets added per batch)
  const char* aB = lds + hi * 3712;            // ci-half offset (4*58*16)
  int woff[6];                                 // ws = owh*3 + kw
  #pragma unroll
  for (int ws = 0; ws < 6; ++ws) {
    int ww = (ws / 3) * 32 + l31 + (ws % 3);
    if (ww > 57) ww = 57;                      // clamp: garbage cols dropped
    woff[ws] = ww * 16;
  }
  const v4i* wbase = Wf + (wn * 2) * 64 + lane;

  // bf(kh, ng) for batch t: Wf[((kh*3+kw)*8+kc)*512 + ng*64]
#define LOADBF(dst, t) do {                                           \
    const int kc_ = (t) / 3, kw_ = (t) % 3;                           \
    _Pragma("unroll")                                                 \
    for (int kh_ = 0; kh_ < 3; ++kh_) {                               \
      (dst)[kh_ * 2 + 0] = wbase[((kh_ * 3 + kw_) * 8 + kc_) * 512];  \
      (dst)[kh_ * 2 + 1] = wbase[((kh_ * 3 + kw_) * 8 + kc_) * 512 + 64]; \
    }                                                                 \
  } while (0)

  v4i bfc[6], bfn[6];
  LOADBF(bfc, 0);

  #pragma unroll
  for (int t = 0; t < 24; ++t) {
    const int kc = t / 3, kw = t % 3;
    // 1) 8 af ds_reads for this (kc,kw): af[rr][owh]
    v4i af[8];
    #pragma unroll
    for (int rr = 0; rr < 4; ++rr)
      #pragma unroll
      for (int owh = 0; owh < 2; ++owh)
        af[rr * 2 + owh] = *(const v4i*)(aB + woff[owh * 3 + kw] +
                                         kc * 7424 + rr * 928);
    // 2) prefetch next batch's bf
    if (t + 1 < 24) LOADBF(bfn, t + 1);
    // 3) 24 MFMAs
    __builtin_amdgcn_s_setprio(1);
    #pragma unroll
    for (int kh = 0; kh < 3; ++kh)
      #pragma unroll
      for (int mg = 0; mg < 4; ++mg) {
        const int rr = (mg >> 1) + kh;
        const int owh = mg & 1;
        acc[mg][0] = __builtin_amdgcn_mfma_i32_32x32x32_i8(af[rr * 2 + owh], bfc[kh * 2 + 0], acc[mg][0], 0, 0, 0);
        acc[mg][1] = __builtin_amdgcn_mfma_i32_32x32x32_i8(af[rr * 2 + owh], bfc[kh * 2 + 1], acc[mg][1], 0, 0, 0);
      }
    __builtin_amdgcn_s_setprio(0);
    // 4) rotate (renamed away by full unroll)
    #pragma unroll
    for (int i = 0; i < 6; ++i) bfc[i] = bfn[i];
  }
#undef LOADBF

  // ---- epilogue: transpose via dead slab, coalesced full-row stores ----
  __syncthreads();
  char* scr = lds + wn * 16896;      // [co 32][m 128 floats] stride 528 B

  #pragma unroll
  for (int ng = 0; ng < 2; ++ng) {
    #pragma unroll
    for (int mg = 0; mg < 4; ++mg) {
      #pragma unroll
      for (int q = 0; q < 4; ++q) {
        float4 f;
        f.x = (float)acc[mg][ng][q * 4 + 0];
        f.y = (float)acc[mg][ng][q * 4 + 1];
        f.z = (float)acc[mg][ng][q * 4 + 2];
        f.w = (float)acc[mg][ng][q * 4 + 3];
        // float idx mi = ohl*64 + owh*32 + q*8 + hi*4  (mg = ohl*2+owh)
        int mib = (mg >> 1) * 256 + (mg & 1) * 128 + q * 32 + hi * 16;
        *(float4*)(scr + l31 * 528 + mib) = f;
      }
    }
    __builtin_amdgcn_s_waitcnt(0);   // lgkm drain before same-wave re-read
    const int co0 = (wn * 2 + ng) * 32;
    #pragma unroll
    for (int t = 0; t < 14; ++t) {
      int f = t * 64 + lane;         // 0..895 = co_l*28 + s
      int co_l = f / 28;
      int s = f - co_l * 28;
      int ohl = (s >= 14) ? 1 : 0;
      int owq = (s - ohl * 14) * 4;  // 0..52
      float4 v = *(const float4*)(scr + co_l * 528 + (ohl * 64 + owq) * 4);
      float* op = out + ((size_t)(b * COUT + co0 + co_l) * H_ + oh0 + ohl) * W_ + owq;
      *(float4*)op = v;
    }
    __builtin_amdgcn_s_waitcnt(0);   // reads done before next ng overwrites
  }
}

// ==================================================================
extern "C" void kernel_launch(void* const* d_in, const int* in_sizes, int n_in,
                              void* d_out, int out_size, void* d_ws, size_t ws_size,
                              hipStream_t stream) {
  const float* x     = (const float*)d_in[0];
  const float* alpha = (const float*)d_in[1];
  const float* wt    = (const float*)d_in[2];
  float* out = (float*)d_out;

  const size_t needA = (size_t)B_ * HP * HP * 256;   // 27,557,888 B
  char* A8 = (char*)d_ws;
  v4i* Wf  = (v4i*)(A8 + needA);

  pack_a8_kernel<<<dim3(15, 32), 256, 0, stream>>>(x, alpha, A8);
  pack_w8_kernel<<<144, 256, 0, stream>>>(wt, Wf);
  conv_mfma_kernel<<<dim3(B_ * 28), 256, 0, stream>>>(A8, Wf, out);
}

// Round 10
// 102.463 us; speedup vs baseline: 1.0662x; 1.0662x over previous
//
#include <hip/hip_runtime.h>
#include <cstdint>

#define B_   32
#define CIN  256
#define COUT 256
#define H_   56
#define W_   56
#define HP   58          // padded spatial dim (pad=1 each side)
#define HW   (H_ * W_)   // 3136

typedef int v4i  __attribute__((ext_vector_type(4)));
typedef int v16i __attribute__((ext_vector_type(16)));

// ==================================================================
// XNOR conv via i8 MFMA: a,w in {+1,-1}; zero-pad = i8 0 (exact).
// ==================================================================

// ---- pack_a8: NCHW fp32 -> padded NHWC i8. A8[b][hh][ww][ci] ----
__global__ __launch_bounds__(256) void pack_a8_kernel(
    const float* __restrict__ x, const float* __restrict__ alpha,
    char* __restrict__ A8) {
  const int w = threadIdx.x & 63;
  const int q = threadIdx.x >> 6;
  const int hh = blockIdx.x * 4 + q;
  const int b = blockIdx.y;
  if (hh >= HP) return;
  char* rowbase = A8 + (size_t)(b * HP + hh) * (HP * 256);
  const uint4 z = make_uint4(0u, 0u, 0u, 0u);
  if (hh == 0 || hh == HP - 1) {           // border row: all zeros
    for (int i = w; i < HP * 16; i += 64) *(uint4*)(rowbase + i * 16) = z;
    return;
  }
  const int h = hh - 1;
  if (w < W_) {
    char* dst = rowbase + (w + 1) * 256;
    const float* xp = x + (size_t)b * CIN * HW + h * W_ + w;
    for (int cw = 0; cw < 16; ++cw) {      // 16B of channels per iter
      uint32_t wd[4];
      #pragma unroll
      for (int u = 0; u < 4; ++u) {
        uint32_t word = 0;
        #pragma unroll
        for (int bb = 0; bb < 4; ++bb) {
          int c = cw * 16 + u * 4 + bb;
          float v = xp[(size_t)c * HW];
          word |= ((v > alpha[c]) ? 0x01u : 0xFFu) << (bb * 8);
        }
        wd[u] = word;
      }
      *(uint4*)(dst + cw * 16) = *(uint4*)wd;
    }
  } else if (w == 56 || w == 57) {         // border pixels ww=0 / ww=57
    char* dst = rowbase + ((w == 56) ? 0 : (HP - 1)) * 256;
    #pragma unroll
    for (int i = 0; i < 16; ++i) *(uint4*)(dst + i * 16) = z;
  }
}

// ---- pack_w8: W in exact B-fragment form (HW-verified, absmax 0) ----
// Wf[((tap*8 + kc)*8 + ng)*64 + lane]: co = ng*32 + (lane&31),
// ci = kc*32 + (lane>>5)*16 + byte j
__global__ __launch_bounds__(256) void pack_w8_kernel(
    const float* __restrict__ wt, v4i* __restrict__ Wf) {
  int id = blockIdx.x * 256 + threadIdx.x;   // 36864 total
  int lane = id & 63;
  int ng = (id >> 6) & 7;
  int kc = (id >> 9) & 7;
  int tap = id >> 12;
  if (tap >= 9) return;
  int kh = tap / 3, kw = tap - kh * 3;
  int co = ng * 32 + (lane & 31);
  int cib = kc * 32 + (lane >> 5) * 16;
  uint32_t wd[4];
  #pragma unroll
  for (int u = 0; u < 4; ++u) {
    uint32_t word = 0;
    #pragma unroll
    for (int bb = 0; bb < 4; ++bb) {
      int ci = cib + u * 4 + bb;
      float v = wt[((size_t)(co * CIN + ci) * 3 + kh) * 3 + kw];
      word |= ((v > 0.0f) ? 0x01u : 0xFFu) << (bb * 8);
    }
    wd[u] = word;
  }
  Wf[id] = *(v4i*)wd;
}

// ---- conv_mfma v7: M128xN32 waves, 3 blocks/CU, decorrelated ----
// Block: 256 thr / 4 waves. Block tile: M128 (4 oh x 32 ow) x N128.
// Wave wn: M128 x N32 (ng = coh*4+wn); acc[4 ohl] v16i = 64 regs.
// Slab [gr16][rr6][ww34] = 52,224 B -> 3 blocks/CU (LDS 156.7KB);
// launch_bounds(256,3) -> <=170 VGPR -> 12 waves/CU from 3 blocks at
// INDEPENDENT phases (the r6-r9 plateau: 2 correlated waves/SIMD).
// Per batch (kc,kw): 6 af ds_reads (rr 0..5), 3 bf L2 loads, 12 MFMAs.
// bf bytes/MFMA = 256 (same L2 economy as r6; r7's regression doubled it).
// ww = l31+kw <= 33: fits 34-window, no clamping at all.
__global__ __launch_bounds__(256, 3) void conv_mfma_kernel(
    const char* __restrict__ A8, const v4i* __restrict__ Wf,
    float* __restrict__ out) {
  __shared__ alignas(16) char lds[52224];   // [gr16][rr6][ww34] x 16B
  const int tid = threadIdx.x;
  const int lane = tid & 63;
  const int l31 = lane & 31;
  const int hi  = lane >> 5;
  const int wn  = tid >> 6;

  // bid = ((b*14 + ohq)*2 + owc)*2 + coh ; XCD-chunked bijective swizzle
  const int bid = blockIdx.x;
  const int wg  = (bid & 7) * 224 + (bid >> 3);   // 1792 = 8*224
  const int coh = wg & 1;
  const int owc = (wg >> 1) & 1;
  const int rest = wg >> 2;
  const int ohq = rest % 14;
  const int b   = rest / 14;
  const int oh0 = ohq * 4;
  const int owbase = owc * 32;

  // ---- fill slab: dst linear i -> ((gr*6+rr)*34+wwl)*16, guarded cols ----
  {
    const char* srcB = A8 + ((size_t)(b * HP + oh0) * HP + owbase) * 256;
    for (int i = tid; i < 16 * 6 * 34; i += 256) {
      int gr  = i / 204;
      int rem = i - gr * 204;
      int rr  = rem / 34;
      int wwl = rem - rr * 34;
      uint4 v = make_uint4(0u, 0u, 0u, 0u);
      if (owbase + wwl < HP)
        v = *(const uint4*)(srcB + ((size_t)rr * HP + wwl) * 256 + gr * 16);
      *(uint4*)(lds + (size_t)i * 16) = v;
    }
  }
  __syncthreads();

  v16i acc[4];
  #pragma unroll
  for (int m = 0; m < 4; ++m)
    #pragma unroll
    for (int e = 0; e < 16; ++e) acc[m][e] = 0;

  // af byte offset = (kc*2+hi)*3264 + rr*544 + (l31+kw)*16
  int aoff[3];
  #pragma unroll
  for (int kw = 0; kw < 3; ++kw) aoff[kw] = hi * 3264 + (l31 + kw) * 16;
  const char* ab = lds;
  const v4i* wb = Wf + (coh * 4 + wn) * 64 + lane;   // ng = coh*4+wn

  #pragma unroll 2
  for (int kc = 0; kc < 8; ++kc) {
    #pragma unroll
    for (int kw = 0; kw < 3; ++kw) {
      v4i af[6];
      #pragma unroll
      for (int rr = 0; rr < 6; ++rr)
        af[rr] = *(const v4i*)(ab + aoff[kw] + kc * 6528 + rr * 544);
      v4i bf[3];
      #pragma unroll
      for (int kh = 0; kh < 3; ++kh)
        bf[kh] = wb[((kh * 3 + kw) * 8 + kc) * 512];
      #pragma unroll
      for (int kh = 0; kh < 3; ++kh)
        #pragma unroll
        for (int ohl = 0; ohl < 4; ++ohl)
          acc[ohl] = __builtin_amdgcn_mfma_i32_32x32x32_i8(
              af[ohl + kh], bf[kh], acc[ohl], 0, 0, 0);
    }
  }

  // ---- epilogue: per-wave transpose via dead slab, row stores ----
  __syncthreads();                   // slab dead for all waves
  char* scr = lds + wn * 4608;       // [co 32] stride 144B x 32 floats
  const int co0 = (coh * 4 + wn) * 32;

  #pragma unroll
  for (int ohl = 0; ohl < 4; ++ohl) {
    #pragma unroll
    for (int q = 0; q < 4; ++q) {
      float4 f;
      f.x = (float)acc[ohl][q * 4 + 0];
      f.y = (float)acc[ohl][q * 4 + 1];
      f.z = (float)acc[ohl][q * 4 + 2];
      f.w = (float)acc[ohl][q * 4 + 3];
      // m = q*8 + hi*4 + j -> byte q*32 + hi*16
      *(float4*)(scr + l31 * 144 + q * 32 + hi * 16) = f;
    }
    asm volatile("s_waitcnt lgkmcnt(0)" ::: "memory");
    __builtin_amdgcn_sched_barrier(0);
    #pragma unroll
    for (int t = 0; t < 4; ++t) {
      int idx = t * 64 + lane;       // 0..255 = co_l*8 + s
      int co_l = idx >> 3;
      int s = idx & 7;
      int ow = owbase + s * 4;
      if (ow + 3 < W_ + 0 && ow < W_) {   // owc=1 drops s>=6
        float4 v = *(const float4*)(scr + co_l * 144 + s * 16);
        float* op = out + ((size_t)(b * COUT + co0 + co_l) * H_ + oh0 + ohl) * W_ + ow;
        *(float4*)op = v;
      }
    }
    asm volatile("s_waitcnt lgkmcnt(0)" ::: "memory");
    __builtin_amdgcn_sched_barrier(0);
  }
}

// ==================================================================
extern "C" void kernel_launch(void* const* d_in, const int* in_sizes, int n_in,
                              void* d_out, int out_size, void* d_ws, size_t ws_size,
                              hipStream_t stream) {
  const float* x     = (const float*)d_in[0];
  const float* alpha = (const float*)d_in[1];
  const float* wt    = (const float*)d_in[2];
  float* out = (float*)d_out;

  const size_t needA = (size_t)B_ * HP * HP * 256;   // 27,557,888 B
  char* A8 = (char*)d_ws;
  v4i* Wf  = (v4i*)(A8 + needA);

  pack_a8_kernel<<<dim3(15, 32), 256, 0, stream>>>(x, alpha, A8);
  pack_w8_kernel<<<144, 256, 0, stream>>>(wt, Wf);
  conv_mfma_kernel<<<dim3(B_ * 14 * 2 * 2), 256, 0, stream>>>(A8, Wf, out);
}